// Round 2
// baseline (1144.338 us; speedup 1.0000x reference)
//
#include <hip/hip_runtime.h>
#include <stdint.h>
#include <stddef.h>

#define N_NODES 24
#define MAX_K   4
#define BATCH   16
#define CIN     64
#define CCH     128
#define HIN     64
#define HH      32
#define PIXELS  (BATCH*HH*HH)          /* 16384 */
#define NODE_ELEMS (BATCH*CCH*HH*HH)   /* 2097152 floats = 8 MB */

/* ---------------- numpy RandomState(42) emulation (host side) ---------------- */
namespace nprng {
struct MT { uint32_t key[624]; int pos; };
static void seed_mt(MT& s, uint32_t sd){
  for(int i=0;i<624;i++){ s.key[i]=sd; sd = 1812433253u*(sd^(sd>>30)) + (uint32_t)i + 1u; }
  s.pos = 624;
}
static void gen(MT& s){
  const uint32_t UP=0x80000000u, LOW=0x7fffffffu, MA=0x9908b0dfu;
  uint32_t y; int i;
  for(i=0;i<227;i++){ y=(s.key[i]&UP)|(s.key[i+1]&LOW); s.key[i]=s.key[i+397]^(y>>1)^((y&1u)?MA:0u); }
  for(;i<623;i++){ y=(s.key[i]&UP)|(s.key[i+1]&LOW); s.key[i]=s.key[i-227]^(y>>1)^((y&1u)?MA:0u); }
  y=(s.key[623]&UP)|(s.key[0]&LOW); s.key[623]=s.key[396]^(y>>1)^((y&1u)?MA:0u);
  s.pos=0;
}
static uint32_t next32(MT& s){
  if(s.pos>=624) gen(s);
  uint32_t y=s.key[s.pos++];
  y^=y>>11; y^=(y<<7)&0x9d2c5680u; y^=(y<<15)&0xefc60000u; y^=y>>18;
  return y;
}
static uint64_t next64(MT& s){ uint64_t hi=next32(s); uint64_t lo=next32(s); return (hi<<32)|lo; }
static uint64_t gen_mask(uint64_t r){ r|=r>>1;r|=r>>2;r|=r>>4;r|=r>>8;r|=r>>16;r|=r>>32; return r; }
/* legacy RandomState.randint(low, high) exclusive, int64 dtype, masked rejection.
   KEY numpy detail (random_bounded_uint64_fill): when rng fits in 32 bits it
   draws SINGLE 32-bit MT words, not (hi<<32)|lo pairs. */
static long long np_randint(MT& s, long long low, long long high){
  uint64_t rng = (uint64_t)(high - 1 - low);
  if(rng==0) return low;                    /* no draw consumed */
  uint64_t mask = gen_mask(rng), v;
  if(rng <= 0xffffffffull){ do { v = (uint64_t)next32(s) & mask; } while(v > rng); }
  else                    { do { v = next64(s) & mask; } while(v > rng); }
  return low + (long long)v;
}
/* distributions.c random_interval: [0, mx], 32-bit draws for mx < 2^32 (used by shuffle) */
static uint64_t np_interval(MT& s, uint64_t mx){
  if(mx==0) return 0;
  uint64_t mask = gen_mask(mx), v;
  if(mx <= 0xffffffffull){ do { v = (uint64_t)next32(s) & mask; } while(v > mx); }
  else                   { do { v = next64(s) & mask; } while(v > mx); }
  return v;
}
} // namespace nprng

/* ---------------- kernels ---------------- */

/* node 0: z = relu(x * sigmoid(agg_w[0,0])); depthwise 3x3 stride 2 SAME (pad_lo=0, pad_hi=1) */
__global__ __launch_bounds__(256)
void k_dw0(const float* __restrict__ x, const float* __restrict__ aggw,
           const float* __restrict__ dwW, float* __restrict__ t)
{
  int blk = blockIdx.x;                 /* 16n * 64c * 4yt = 4096 */
  int yt = blk & 3, c = (blk>>2)&63, n = blk>>8;
  int tid = threadIdx.x, lx = tid&31, ly = tid>>5;
  float g = 1.0f/(1.0f + expf(-aggw[0]));
  __shared__ float z[17][65];
  const float* xp = x + ((size_t)(n*64 + c))*HIN*HIN;
  int iy0 = yt*16;
  for(int idx=tid; idx<17*65; idx+=256){
    int r = idx/65, q = idx - r*65;
    int iy = iy0 + r, ix = q;
    float v = 0.0f;
    if(iy < 64 && ix < 64) v = xp[iy*64 + ix] * g;
    z[r][q] = v > 0.0f ? v : 0.0f;
  }
  __syncthreads();
  float w[9];
#pragma unroll
  for(int q=0;q<9;q++) w[q] = dwW[q*64 + c];   /* dw0[ky][kx][0][c] */
  float acc = 0.0f;
#pragma unroll
  for(int ky=0;ky<3;ky++)
#pragma unroll
    for(int kx=0;kx<3;kx++)
      acc += w[ky*3+kx] * z[2*ly+ky][2*lx+kx];
  t[(((size_t)n*64 + c)*32 + (yt*8+ly))*32 + lx] = acc;
}

/* nodes >=1: z = relu(sum_k sigmoid(aggw[k]) * pred_k); depthwise 3x3 stride 1 SAME */
__global__ __launch_bounds__(256)
void k_dw(const float* __restrict__ p0, const float* __restrict__ p1,
          const float* __restrict__ p2, const float* __restrict__ p3,
          int k, const float* __restrict__ aggw, const float* __restrict__ dwW,
          float* __restrict__ t)
{
  int blk = blockIdx.x;                 /* 16n * 128c * 4yt = 8192 */
  int yt = blk & 3, c = (blk>>2)&127, n = blk>>9;
  int tid = threadIdx.x, lx = tid&31, ly = tid>>5;
  float w0 = 1.0f/(1.0f + expf(-aggw[0]));
  float w1 = (k>1) ? 1.0f/(1.0f + expf(-aggw[1])) : 0.0f;
  float w2 = (k>2) ? 1.0f/(1.0f + expf(-aggw[2])) : 0.0f;
  float w3 = (k>3) ? 1.0f/(1.0f + expf(-aggw[3])) : 0.0f;
  __shared__ float z[10][34];
  size_t base = ((size_t)(n*128 + c))*1024;
  int iy0 = yt*8 - 1;
  for(int idx=tid; idx<10*34; idx+=256){
    int r = idx/34, q = idx - r*34;
    int iy = iy0 + r, ix = q - 1;
    float v = 0.0f;
    if(iy>=0 && iy<32 && ix>=0 && ix<32){
      size_t off = base + iy*32 + ix;
      v = w0*p0[off];
      if(k>1) v += w1*p1[off];
      if(k>2) v += w2*p2[off];
      if(k>3) v += w3*p3[off];
    }
    z[r][q] = v > 0.0f ? v : 0.0f;
  }
  __syncthreads();
  float w[9];
#pragma unroll
  for(int q=0;q<9;q++) w[q] = dwW[q*128 + c];
  float acc = 0.0f;
#pragma unroll
  for(int ky=0;ky<3;ky++)
#pragma unroll
    for(int kx=0;kx<3;kx++)
      acc += w[ky*3+kx] * z[ly+ky][lx+kx];
  t[base + (yt*8+ly)*32 + lx] = acc;
}

/* pointwise 1x1 (K in-channels -> 128 out) + BN affine */
template<int K>
__global__ __launch_bounds__(256)
void k_pw(const float* __restrict__ t, const float* __restrict__ W,
          const float* __restrict__ gamma, const float* __restrict__ beta,
          float* __restrict__ out)
{
  __shared__ float ts[K][32];
  int p0 = blockIdx.x * 32;             /* 512 blocks of 32 pixels */
  int tid = threadIdx.x, px = tid&31, cog = tid>>5;
  for(int idx=tid; idx<K*32; idx+=256){
    int ci = idx>>5, q = idx&31;
    int pp = p0 + q, nn = pp>>10, yy = pp&1023;
    ts[ci][q] = t[((size_t)nn*K + ci)*1024 + yy];
  }
  __syncthreads();
  float acc[16];
#pragma unroll
  for(int j=0;j<16;j++) acc[j]=0.0f;
  for(int ci=0;ci<K;ci++){
    float tv = ts[ci][px];
    const float4* w4 = (const float4*)(W + ci*128 + cog*16);
    float4 a = w4[0], b = w4[1], c2 = w4[2], d = w4[3];
    acc[0]+=tv*a.x;  acc[1]+=tv*a.y;  acc[2]+=tv*a.z;  acc[3]+=tv*a.w;
    acc[4]+=tv*b.x;  acc[5]+=tv*b.y;  acc[6]+=tv*b.z;  acc[7]+=tv*b.w;
    acc[8]+=tv*c2.x; acc[9]+=tv*c2.y; acc[10]+=tv*c2.z;acc[11]+=tv*c2.w;
    acc[12]+=tv*d.x; acc[13]+=tv*d.y; acc[14]+=tv*d.z; acc[15]+=tv*d.w;
  }
  int p = p0 + px, n = p>>10, yx = p&1023;
  float* op = out + (size_t)n*CCH*1024 + yx;
#pragma unroll
  for(int j=0;j<16;j++){
    int co = cog*16 + j;
    op[(size_t)co*1024] = acc[j]*gamma[co] + beta[co];
  }
}

struct PtrList { const float* p[N_NODES]; int n; };

__global__ __launch_bounds__(256)
void k_mean(PtrList pl, float scale, float* __restrict__ out, int nelem)
{
  int i = blockIdx.x*256 + threadIdx.x;
  if(i >= nelem) return;
  float s = 0.0f;
  for(int j=0;j<pl.n;j++) s += pl.p[j][i];
  out[i] = s*scale;
}

/* ---------------- host ---------------- */
extern "C" void kernel_launch(void* const* d_in, const int* in_sizes, int n_in,
                              void* d_out, int out_size, void* d_ws, size_t ws_size,
                              hipStream_t stream)
{
  const float* x     = (const float*)d_in[0];
  const float* aggw  = (const float*)d_in[1];
  const float* dw0   = (const float*)d_in[2];
  const float* pw0   = (const float*)d_in[3];
  const float* dw    = (const float*)d_in[4];
  const float* pw    = (const float*)d_in[5];
  const float* gamma = (const float*)d_in[6];
  const float* beta  = (const float*)d_in[7];
  float* out = (float*)d_out;

  /* rebuild the reference's static DAG: np.random.RandomState(42) */
  int preds[N_NODES][MAX_K]; int npred[N_NODES];
  {
    nprng::MT st; nprng::seed_mt(st, 42u);
    npred[0] = 0;
    for(int i=1;i<N_NODES;i++){
      int mx = (i < MAX_K) ? i : MAX_K;
      int k = (int)nprng::np_randint(st, 1, (long long)mx + 1);
      int perm[N_NODES];
      for(int q=0;q<i;q++) perm[q]=q;
      for(int q=i-1;q>=1;q--){
        int j = (int)nprng::np_interval(st, (uint64_t)q);
        int tt = perm[q]; perm[q] = perm[j]; perm[j] = tt;
      }
      /* first k, sorted */
      int tmp[MAX_K];
      for(int a=0;a<k;a++) tmp[a]=perm[a];
      for(int a=1;a<k;a++){ int v=tmp[a]; int b=a-1; while(b>=0 && tmp[b]>v){ tmp[b+1]=tmp[b]; b--; } tmp[b+1]=v; }
      npred[i]=k;
      for(int a=0;a<k;a++) preds[i][a]=tmp[a];
    }
  }

  /* sinks + liveness-based slot assignment */
  int uses[N_NODES]; bool sink[N_NODES]; int rem[N_NODES];
  for(int i=0;i<N_NODES;i++) uses[i]=0;
  for(int i=0;i<N_NODES;i++) for(int q=0;q<npred[i];q++) uses[preds[i][q]]++;
  int nsinks=0;
  for(int i=0;i<N_NODES;i++){ sink[i] = (uses[i]==0); if(sink[i]) nsinks++; rem[i] = uses[i] + (sink[i]?1:0); }

  /* dry pass: compute number of slots needed */
  int slot_of[N_NODES]; bool slot_free[N_NODES]; int nslots=0;
  {
    int rem2[N_NODES]; for(int i=0;i<N_NODES;i++){ rem2[i]=rem[i]; slot_free[i]=false; }
    for(int i=0;i<N_NODES;i++){
      int s=-1; for(int q=0;q<nslots;q++) if(slot_free[q]){ s=q; break; }
      if(s<0) s = nslots++;
      slot_free[s]=false; slot_of[i]=s;
      for(int q=0;q<npred[i];q++){ int p=preds[i][q]; if(--rem2[p]==0) slot_free[slot_of[p]]=true; }
    }
  }

  float* tbuf = (float*)d_ws;                      /* 8 MB scratch for depthwise output */
  float* slotbase = tbuf + (size_t)NODE_ELEMS;
  size_t needed = ((size_t)(1 + nslots)) * NODE_ELEMS * sizeof(float);
  if(ws_size < needed) return;   /* distinct failure signature: out stays zero */

  /* launch nodes in order (stream serializes the DAG) */
  for(int i=0;i<N_NODES;i++){
    float* outp = slotbase + (size_t)slot_of[i]*NODE_ELEMS;
    if(i==0){
      k_dw0<<<dim3(16*64*4), dim3(256), 0, stream>>>(x, aggw, dw0, tbuf);
      k_pw<64><<<dim3(PIXELS/32), dim3(256), 0, stream>>>(tbuf, pw0, gamma, beta, outp);
    } else {
      const float* pp[4];
      for(int q=0;q<4;q++){
        int src = preds[i][(q<npred[i])?q:0];
        pp[q] = slotbase + (size_t)slot_of[src]*NODE_ELEMS;
      }
      k_dw<<<dim3(16*128*4), dim3(256), 0, stream>>>(pp[0],pp[1],pp[2],pp[3],
            npred[i], aggw + i*4, dw + (size_t)(i-1)*9*128, tbuf);
      k_pw<128><<<dim3(PIXELS/32), dim3(256), 0, stream>>>(tbuf, pw + (size_t)(i-1)*128*128,
            gamma + i*128, beta + i*128, outp);
    }
  }

  /* final mean over sinks */
  PtrList pl; pl.n = 0;
  for(int i=0;i<N_NODES;i++) if(sink[i]) pl.p[pl.n++] = slotbase + (size_t)slot_of[i]*NODE_ELEMS;
  k_mean<<<dim3((NODE_ELEMS+255)/256), dim3(256), 0, stream>>>(pl, 1.0f/(float)pl.n, out, NODE_ELEMS);
}